// Round 9
// baseline (379.066 us; speedup 1.0000x reference)
//
#include <hip/hip_runtime.h>

#define NN 12800
#define NE 204800

// ---------------- static device scratch (~42 MB) ----------------
__device__ __align__(16) float g_outA[NN * 16];  // node features ping
__device__ __align__(16) float g_outB[NN * 16];  // node features pong
__device__ __align__(16) float g_ehs[NE * 16];   // edge hidden, DST-sorted order
__device__ __align__(16) float g_osgA[NE * 16];  // gathered src feats (edge order) ping
__device__ __align__(16) float g_osgB[NE * 16];  // gathered src feats pong
__device__ int g_src[NE];                        // src per dst-sorted edge
__device__ int g_dcnt[NN];                       // in-degree
__device__ int g_rowp[NN];                       // dst-CSR row start
__device__ int g_cur[NN];                        // dst scatter cursor
__device__ int g_scnt[NN];                       // out-degree
__device__ int g_srowp[NN];                      // src-CSR row start
__device__ int g_scur[NN];                       // src scatter cursor
__device__ int g_sedge[NE];                      // dst-sorted positions, grouped by src

// ---- S0: out0 = relu(x @ lin0_w.T + b); zero counters ----
__global__ __launch_bounds__(256) void k_setup(const float* __restrict__ x,
                                               const float* __restrict__ lw,
                                               const float* __restrict__ lb) {
    int n = blockIdx.x * 256 + threadIdx.x;
    float x0 = x[n * 3 + 0], x1 = x[n * 3 + 1], x2 = x[n * 3 + 2];
    float v[16];
#pragma unroll
    for (int j = 0; j < 16; ++j) {
        float t = lb[j] + x0 * lw[j * 3 + 0] + x1 * lw[j * 3 + 1] + x2 * lw[j * 3 + 2];
        v[j] = fmaxf(t, 0.0f);
    }
#pragma unroll
    for (int j = 0; j < 16; j += 4)
        *(float4*)(g_outA + n * 16 + j) = make_float4(v[j], v[j + 1], v[j + 2], v[j + 3]);
    g_dcnt[n] = 0;
    g_scnt[n] = 0;
}

// ---- S1: count dst / src occurrences ----
__global__ __launch_bounds__(256) void k_count(const int* __restrict__ ei) {
    int e = blockIdx.x * 256 + threadIdx.x;
    atomicAdd(&g_scnt[ei[e]], 1);
    atomicAdd(&g_dcnt[ei[NE + e]], 1);
}

// ---- S2: exclusive scans: dcnt -> rowp/cur, scnt -> srowp/scur ----
__global__ __launch_bounds__(256) void k_scan() {
    __shared__ int partd[256], parts[256];
    const int C = NN / 256;  // 50
    int t = threadIdx.x;
    int sumd = 0, sums = 0;
    for (int i = 0; i < C; ++i) { sumd += g_dcnt[t * C + i]; sums += g_scnt[t * C + i]; }
    partd[t] = sumd; parts[t] = sums;
    __syncthreads();
    for (int off = 1; off < 256; off <<= 1) {
        int vd = (t >= off) ? partd[t - off] : 0;
        int vs = (t >= off) ? parts[t - off] : 0;
        __syncthreads();
        partd[t] += vd; parts[t] += vs;
        __syncthreads();
    }
    int rund = (t > 0) ? partd[t - 1] : 0;
    int runs = (t > 0) ? parts[t - 1] : 0;
    for (int i = 0; i < C; ++i) {
        int idx = t * C + i;
        g_rowp[idx] = rund; g_cur[idx] = rund; rund += g_dcnt[idx];
        g_srowp[idx] = runs; g_scur[idx] = runs; runs += g_scnt[idx];
    }
}

// ---- S3: eh -> dst-sorted slot; build src-CSR of dst-sorted positions ----
__global__ __launch_bounds__(256) void k_scatter(const int* __restrict__ ei,
                                                 const float* __restrict__ attr,
                                                 const float* __restrict__ w1,
                                                 const float* __restrict__ b1) {
    int e = blockIdx.x * 256 + threadIdx.x;
    int s = ei[e], d = ei[NE + e];
    float4 a = *(const float4*)(attr + e * 4);
    float v[16];
#pragma unroll
    for (int j = 0; j < 16; ++j) {
        float t = b1[j] + a.x * w1[j * 4 + 0] + a.y * w1[j * 4 + 1] +
                  a.z * w1[j * 4 + 2] + a.w * w1[j * 4 + 3];
        v[j] = fmaxf(t, 0.0f);
    }
    int pos = atomicAdd(&g_cur[d], 1);
    g_src[pos] = s;
#pragma unroll
    for (int j = 0; j < 16; j += 4)
        *(float4*)(g_ehs + pos * 16 + j) = make_float4(v[j], v[j + 1], v[j + 2], v[j + 3]);
    int spos = atomicAdd(&g_scur[s], 1);
    g_sedge[spos] = pos;
}

// ---- S4: initial edge-order gather (edge-parallel, latency-tolerant) ----
__global__ __launch_bounds__(256) void k_gather0() {
    int t = threadIdx.x;
    int p = blockIdx.x * 16 + (t >> 4);
    int k = t & 15;
    g_osgA[p * 16 + k] = g_outA[g_src[p] * 16 + k];
}

// ---- one round, one dispatch. 256 thr = 16 nodes x 16 lanes (R6 shape). ----
// Edge loop now streams osg/ehs at sequential addresses (no dependent-address
// chain). Node phase scatter-writes hnew into osg_next at this node's
// out-edge slots (src-CSR), replacing next round's gather.
__global__ __launch_bounds__(256) void k_round(const float* __restrict__ nn2_w,
                                               const float* __restrict__ nn2_b,
                                               const float* __restrict__ cr,
                                               const float* __restrict__ cb,
                                               const float* __restrict__ wi,
                                               const float* __restrict__ wh,
                                               const float* __restrict__ bi,
                                               const float* __restrict__ bh,
                                               float* __restrict__ out_final,
                                               int flip, int last) {
    __shared__ float s_W2e[17 * 256];            // [j][d*16+k], j=16 -> nn2_b
    __shared__ float s_cr[256], s_wiT[768], s_whT[768];
    __shared__ float s_cb[16], s_bi[48], s_bh[48];
    __shared__ float s_G[16][272];               // per-group staging (17x16)

    int t = threadIdx.x;
    for (int i = t; i < 17 * 256; i += 256) {
        int j = i >> 8, r = i & 255;
        s_W2e[i] = (j < 16) ? nn2_w[r * 16 + j] : nn2_b[r];
    }
    s_cr[t] = cr[t];                             // [d*16+k]
    for (int i = t; i < 768; i += 256) {
        int row = i >> 4, d = i & 15;
        s_wiT[d * 48 + row] = wi[i];
        s_whT[d * 48 + row] = wh[i];
    }
    if (t < 16) s_cb[t] = cb[t];
    if (t < 48) { s_bi[t] = bi[t]; s_bh[t] = bh[t]; }
    __syncthreads();

    const float* cur  = flip ? g_outB : g_outA;
    float*       nxt  = flip ? g_outA : g_outB;
    const float* osg  = flip ? g_osgB : g_osgA;
    float*       osgn = flip ? g_osgA : g_osgB;

    int grp = t >> 4, k = t & 15;
    int n = blockIdx.x * 16 + grp;
    int start = g_rowp[n];
    int deg   = g_dcnt[n];

    // ---- G accumulation: sequential streaming reads, no address deps ----
    float Gk[17];
#pragma unroll
    for (int j = 0; j < 17; ++j) Gk[j] = 0.0f;
#pragma unroll 4
    for (int q = 0; q < deg; ++q) {
        int p = start + q;
        float ok = osg[p * 16 + k];              // 64B coalesced per group, sequential
        float4 e0 = *(const float4*)(g_ehs + p * 16 + 0);   // broadcast, sequential
        float4 e1 = *(const float4*)(g_ehs + p * 16 + 4);
        float4 e2 = *(const float4*)(g_ehs + p * 16 + 8);
        float4 e3 = *(const float4*)(g_ehs + p * 16 + 12);
        Gk[0]  += e0.x * ok; Gk[1]  += e0.y * ok; Gk[2]  += e0.z * ok; Gk[3]  += e0.w * ok;
        Gk[4]  += e1.x * ok; Gk[5]  += e1.y * ok; Gk[6]  += e1.z * ok; Gk[7]  += e1.w * ok;
        Gk[8]  += e2.x * ok; Gk[9]  += e2.y * ok; Gk[10] += e2.z * ok; Gk[11] += e2.w * ok;
        Gk[12] += e3.x * ok; Gk[13] += e3.y * ok; Gk[14] += e3.z * ok; Gk[15] += e3.w * ok;
        Gk[16] += ok;                            // bias row (eh == 1)
    }

    // ---- stage G to LDS (same-wave ordering, no barrier needed) ----
    float* Gs = &s_G[grp][0];
#pragma unroll
    for (int j = 0; j < 17; ++j) Gs[j * 16 + k] = Gk[j];

    // ---- contraction with W2e ----
    float acc = 0.0f;
#pragma unroll 1
    for (int j = 0; j < 17; ++j) {
#pragma unroll
        for (int d = 0; d < 16; ++d)
            acc += Gs[j * 16 + d] * s_W2e[j * 256 + d * 16 + k];
    }
    float invd = 1.0f / (float)(deg > 0 ? deg : 1);
    float a_k = acc * invd;

    // ---- node update ----
    float o[16];
#pragma unroll
    for (int d = 0; d < 16; d += 4) {
        float4 v = *(const float4*)(cur + n * 16 + d);      // broadcast per group
        o[d] = v.x; o[d + 1] = v.y; o[d + 2] = v.z; o[d + 3] = v.w;
    }
    float mcc = s_cb[k] + a_k;
#pragma unroll
    for (int d = 0; d < 16; ++d) mcc += o[d] * s_cr[d * 16 + k];
    float m = fmaxf(mcc, 0.0f);

    Gs[k] = m;                                   // reuse staging (same-wave order)
    float md[16];
#pragma unroll
    for (int d = 0; d < 16; ++d) md[d] = Gs[d];

    float ir = s_bi[k], iz = s_bi[16 + k], in_ = s_bi[32 + k];
    float hr = s_bh[k], hz = s_bh[16 + k], hh = s_bh[32 + k];
#pragma unroll
    for (int d = 0; d < 16; ++d) {
        ir  += md[d] * s_wiT[d * 48 + k];
        iz  += md[d] * s_wiT[d * 48 + 16 + k];
        in_ += md[d] * s_wiT[d * 48 + 32 + k];
        hr  += o[d] * s_whT[d * 48 + k];
        hz  += o[d] * s_whT[d * 48 + 16 + k];
        hh  += o[d] * s_whT[d * 48 + 32 + k];
    }
    float rg = 1.0f / (1.0f + __expf(-(ir + hr)));
    float z  = 1.0f / (1.0f + __expf(-(iz + hz)));
    float nh = tanhf(in_ + rg * hh);
    float hnew = (1.0f - z) * nh + z * o[k];

    if (last) {
        out_final[n * 16 + k] = hnew;
    } else {
        nxt[n * 16 + k] = hnew;
        // scatter hnew into next round's gathered-src buffer (fire-and-forget)
        int ss = g_srowp[n];
        int sd = g_scnt[n];
        for (int i = 0; i < sd; ++i) {
            int p2 = g_sedge[ss + i];            // sequential read, broadcast
            osgn[p2 * 16 + k] = hnew;            // random 64B store per group
        }
    }
}

extern "C" void kernel_launch(void* const* d_in, const int* in_sizes, int n_in,
                              void* d_out, int out_size, void* d_ws, size_t ws_size,
                              hipStream_t stream) {
    const float* x         = (const float*)d_in[0];
    const int*   ei        = (const int*)d_in[1];
    const float* edge_attr = (const float*)d_in[2];
    const float* lin0_w    = (const float*)d_in[3];
    const float* lin0_b    = (const float*)d_in[4];
    const float* nn1_w     = (const float*)d_in[5];
    const float* nn1_b     = (const float*)d_in[6];
    const float* nn2_w     = (const float*)d_in[7];
    const float* nn2_b     = (const float*)d_in[8];
    const float* conv_root = (const float*)d_in[9];
    const float* conv_bias = (const float*)d_in[10];
    const float* gru_w_ih  = (const float*)d_in[11];
    const float* gru_w_hh  = (const float*)d_in[12];
    const float* gru_b_ih  = (const float*)d_in[13];
    const float* gru_b_hh  = (const float*)d_in[14];
    float* out = (float*)d_out;

    k_setup<<<NN / 256, 256, 0, stream>>>(x, lin0_w, lin0_b);
    k_count<<<NE / 256, 256, 0, stream>>>(ei);
    k_scan<<<1, 256, 0, stream>>>();
    k_scatter<<<NE / 256, 256, 0, stream>>>(ei, edge_attr, nn1_w, nn1_b);
    k_gather0<<<NE / 16, 256, 0, stream>>>();

    for (int r = 0; r < 6; ++r) {
        k_round<<<NN / 16, 256, 0, stream>>>(nn2_w, nn2_b, conv_root, conv_bias,
                                             gru_w_ih, gru_w_hh, gru_b_ih, gru_b_hh,
                                             out, r & 1, r == 5 ? 1 : 0);
    }
}

// Round 10
// 267.754 us; speedup vs baseline: 1.4157x; 1.4157x over previous
//
#include <hip/hip_runtime.h>

#define NN 12800
#define NE 204800

// ---------------- static device scratch (~14.5 MB) ----------------
__device__ __align__(16) float g_outA[NN * 16];  // node features ping
__device__ __align__(16) float g_outB[NN * 16];  // node features pong
__device__ __align__(16) float g_ehs[NE * 16];   // edge hidden, DST-sorted order
__device__ int g_src[NE];                        // src per dst-sorted edge
__device__ int g_dcnt[NN];                       // in-degree (zeroed by last round of prev call; zero-init at load)
__device__ int g_rowp[NN];                       // dst-CSR row start
__device__ int g_cur[NN];                        // dst scatter cursor

// ---- S0: count dst (edge-parallel) + lin0 init (node range) -- disjoint arrays
__global__ __launch_bounds__(256) void k_pre(const int* __restrict__ ei,
                                             const float* __restrict__ x,
                                             const float* __restrict__ lw,
                                             const float* __restrict__ lb) {
    int gid = blockIdx.x * 256 + threadIdx.x;
    atomicAdd(&g_dcnt[ei[NE + gid]], 1);
    if (gid < NN) {
        int n = gid;
        float x0 = x[n * 3 + 0], x1 = x[n * 3 + 1], x2 = x[n * 3 + 2];
        float v[16];
#pragma unroll
        for (int j = 0; j < 16; ++j) {
            float t = lb[j] + x0 * lw[j * 3 + 0] + x1 * lw[j * 3 + 1] + x2 * lw[j * 3 + 2];
            v[j] = fmaxf(t, 0.0f);
        }
#pragma unroll
        for (int j = 0; j < 16; j += 4)
            *(float4*)(g_outA + n * 16 + j) = make_float4(v[j], v[j + 1], v[j + 2], v[j + 3]);
    }
}

// ---- S1: exclusive scan dcnt -> rowp, cur ----
__global__ __launch_bounds__(256) void k_scan() {
    __shared__ int part[256];
    const int C = NN / 256;  // 50
    int t = threadIdx.x;
    int sum = 0;
    for (int i = 0; i < C; ++i) sum += g_dcnt[t * C + i];
    part[t] = sum;
    __syncthreads();
    for (int off = 1; off < 256; off <<= 1) {
        int v = (t >= off) ? part[t - off] : 0;
        __syncthreads();
        part[t] += v;
        __syncthreads();
    }
    int run = (t > 0) ? part[t - 1] : 0;
    for (int i = 0; i < C; ++i) {
        int idx = t * C + i;
        g_rowp[idx] = run;
        g_cur[idx] = run;
        run += g_dcnt[idx];
    }
}

// ---- S2: eh = relu(attr @ nn1_w.T + b1); scatter into dst-sorted slot ----
__global__ __launch_bounds__(256) void k_scatter(const int* __restrict__ ei,
                                                 const float* __restrict__ attr,
                                                 const float* __restrict__ w1,
                                                 const float* __restrict__ b1) {
    int e = blockIdx.x * 256 + threadIdx.x;
    int s = ei[e], d = ei[NE + e];
    float4 a = *(const float4*)(attr + e * 4);
    float v[16];
#pragma unroll
    for (int j = 0; j < 16; ++j) {
        float t = b1[j] + a.x * w1[j * 4 + 0] + a.y * w1[j * 4 + 1] +
                  a.z * w1[j * 4 + 2] + a.w * w1[j * 4 + 3];
        v[j] = fmaxf(t, 0.0f);
    }
    int pos = atomicAdd(&g_cur[d], 1);
    g_src[pos] = s;
#pragma unroll
    for (int j = 0; j < 16; j += 4)
        *(float4*)(g_ehs + pos * 16 + j) = make_float4(v[j], v[j + 1], v[j + 2], v[j + 3]);
}

// ---- one round, one dispatch. 256 thr = 16 nodes x 16 lanes. ----
// Lane j owns G ROW j in registers: Gd[d] = sum_e eh[e,j]*out[src_e,d];
// r16 = sum_e out[src_e,j] (bias row element d=j).
// Contraction: part[k'] = sum_d Gd[d]*W2[(d,k'),j] + r16*b2[j*16+k']  (b128 LDS).
// 16x17 LDS transpose reduces over j; then conv+GRU with b128 weight reads.
__global__ __launch_bounds__(256) void k_round(const float* __restrict__ nn2_w,
                                               const float* __restrict__ nn2_b,
                                               const float* __restrict__ cr,
                                               const float* __restrict__ cb,
                                               const float* __restrict__ wi,
                                               const float* __restrict__ wh,
                                               const float* __restrict__ bi,
                                               const float* __restrict__ bh,
                                               float* __restrict__ out_final,
                                               int flip, int last) {
    // s_W2[j*276 + k'*16 + d] = nn2_w[(d*16+k')*16+j]; bias at [j*276+256+k]
    __shared__ float s_W2[16 * 276];
    __shared__ float s_T[16 * 292];              // per-group 17x17-ish transpose pad
    __shared__ float s_crT[16 * 20];             // [k*20+d] = cr[d*16+k]
    __shared__ float s_wi[48 * 20], s_wh[48 * 20];  // [row*20+d]
    __shared__ float s_cb[16], s_bi[48], s_bh[48];

    int t = threadIdx.x;
    for (int i = t; i < 4096; i += 256) {
        float v = nn2_w[i];
        int j = i & 15, mm = i >> 4, kp = mm & 15, d = mm >> 4;
        s_W2[j * 276 + kp * 16 + d] = v;
    }
    s_W2[(t >> 4) * 276 + 256 + (t & 15)] = nn2_b[t];
    if (t < 256) s_crT[(t & 15) * 20 + (t >> 4)] = cr[t];
    for (int i = t; i < 768; i += 256) {
        s_wi[(i >> 4) * 20 + (i & 15)] = wi[i];
        s_wh[(i >> 4) * 20 + (i & 15)] = wh[i];
    }
    if (t < 16) s_cb[t] = cb[t];
    if (t < 48) { s_bi[t] = bi[t]; s_bh[t] = bh[t]; }
    __syncthreads();

    const float* cur = flip ? g_outB : g_outA;
    float*       nxt = flip ? g_outA : g_outB;

    const int grp = t >> 4, j = t & 15;          // lane j inside group
    const int n = blockIdx.x * 16 + grp;
    const int start = g_rowp[n];
    const int deg   = g_dcnt[n];
    if (last && j == 0) g_dcnt[n] = 0;           // reset for next call's k_pre

    // ---- G-row accumulation (registers, zero LDS) ----
    float Gd[16];
#pragma unroll
    for (int d = 0; d < 16; ++d) Gd[d] = 0.0f;
    float r16 = 0.0f;
#pragma unroll 4
    for (int p = start; p < start + deg; ++p) {
        int s = g_src[p];                        // group-uniform
        const float* orow = cur + s * 16;
        float ej = g_ehs[p * 16 + j];            // coalesced 64B per group
        float4 o0 = *(const float4*)(orow + 0);  // broadcast
        float4 o1 = *(const float4*)(orow + 4);
        float4 o2 = *(const float4*)(orow + 8);
        float4 o3 = *(const float4*)(orow + 12);
        Gd[0]  += ej * o0.x; Gd[1]  += ej * o0.y; Gd[2]  += ej * o0.z; Gd[3]  += ej * o0.w;
        Gd[4]  += ej * o1.x; Gd[5]  += ej * o1.y; Gd[6]  += ej * o1.z; Gd[7]  += ej * o1.w;
        Gd[8]  += ej * o2.x; Gd[9]  += ej * o2.y; Gd[10] += ej * o2.z; Gd[11] += ej * o2.w;
        Gd[12] += ej * o3.x; Gd[13] += ej * o3.y; Gd[14] += ej * o3.z; Gd[15] += ej * o3.w;
        r16 += orow[j];                          // coalesced b32 (same line)
    }

    // ---- contraction: part[k'] via b128 LDS reads (2-way aliasing only) ----
    const float* wj = s_W2 + j * 276;
    float part[16];
#pragma unroll
    for (int kp = 0; kp < 16; ++kp) {
        const float* w = wj + kp * 16;
        float4 w0 = *(const float4*)(w + 0);
        float4 w1 = *(const float4*)(w + 4);
        float4 w2 = *(const float4*)(w + 8);
        float4 w3 = *(const float4*)(w + 12);
        float acc = Gd[0] * w0.x + Gd[1] * w0.y + Gd[2] * w0.z + Gd[3] * w0.w
                  + Gd[4] * w1.x + Gd[5] * w1.y + Gd[6] * w1.z + Gd[7] * w1.w
                  + Gd[8] * w2.x + Gd[9] * w2.y + Gd[10] * w2.z + Gd[11] * w2.w
                  + Gd[12] * w3.x + Gd[13] * w3.y + Gd[14] * w3.z + Gd[15] * w3.w;
        part[kp] = acc;
    }
    {   // fold bias row: part[k] += r16 * b2[j*16+k]
        float4 b0 = *(const float4*)(wj + 256);
        float4 b1 = *(const float4*)(wj + 260);
        float4 b2v = *(const float4*)(wj + 264);
        float4 b3 = *(const float4*)(wj + 268);
        part[0] += r16 * b0.x; part[1] += r16 * b0.y; part[2] += r16 * b0.z; part[3] += r16 * b0.w;
        part[4] += r16 * b1.x; part[5] += r16 * b1.y; part[6] += r16 * b1.z; part[7] += r16 * b1.w;
        part[8] += r16 * b2v.x; part[9] += r16 * b2v.y; part[10] += r16 * b2v.z; part[11] += r16 * b2v.w;
        part[12] += r16 * b3.x; part[13] += r16 * b3.y; part[14] += r16 * b3.z; part[15] += r16 * b3.w;
    }

    // ---- transpose-reduce over j (same-wave LDS, no barrier) ----
    float* Ts = s_T + grp * 292;
#pragma unroll
    for (int k2 = 0; k2 < 16; ++k2) Ts[j * 17 + k2] = part[k2];
    float aggr = 0.0f;
#pragma unroll
    for (int j2 = 0; j2 < 16; ++j2) aggr += Ts[j2 * 17 + j];
    float invd = 1.0f / (float)(deg > 0 ? deg : 1);
    float a_k = aggr * invd;                     // lane j == output k from here on
    const int k = j;

    // ---- node update: o row (broadcast), conv, GRU (all b128 weights) ----
    const float* nrow = cur + n * 16;
    float4 q0 = *(const float4*)(nrow + 0);
    float4 q1 = *(const float4*)(nrow + 4);
    float4 q2 = *(const float4*)(nrow + 8);
    float4 q3 = *(const float4*)(nrow + 12);
    float o[16] = {q0.x, q0.y, q0.z, q0.w, q1.x, q1.y, q1.z, q1.w,
                   q2.x, q2.y, q2.z, q2.w, q3.x, q3.y, q3.z, q3.w};
    float ok = nrow[k];                          // own component (coalesced)

    float mcc = s_cb[k] + a_k;
    {
        const float* c = s_crT + k * 20;
        float4 c0 = *(const float4*)(c + 0);
        float4 c1 = *(const float4*)(c + 4);
        float4 c2 = *(const float4*)(c + 8);
        float4 c3 = *(const float4*)(c + 12);
        mcc += o[0] * c0.x + o[1] * c0.y + o[2] * c0.z + o[3] * c0.w
             + o[4] * c1.x + o[5] * c1.y + o[6] * c1.z + o[7] * c1.w
             + o[8] * c2.x + o[9] * c2.y + o[10] * c2.z + o[11] * c2.w
             + o[12] * c3.x + o[13] * c3.y + o[14] * c3.z + o[15] * c3.w;
    }
    float m = fmaxf(mcc, 0.0f);

    // broadcast m across group via s_T row 16 (same-wave ordering)
    Ts[272 + k] = m;
    float4 m0 = *(const float4*)(Ts + 272);
    float4 m1 = *(const float4*)(Ts + 276);
    float4 m2 = *(const float4*)(Ts + 280);
    float4 m3 = *(const float4*)(Ts + 284);
    float md[16] = {m0.x, m0.y, m0.z, m0.w, m1.x, m1.y, m1.z, m1.w,
                    m2.x, m2.y, m2.z, m2.w, m3.x, m3.y, m3.z, m3.w};

    float ir = s_bi[k], iz = s_bi[16 + k], in_ = s_bi[32 + k];
    float hr = s_bh[k], hz = s_bh[16 + k], hh = s_bh[32 + k];
#pragma unroll
    for (int g = 0; g < 3; ++g) {
        const float* wrow_i = s_wi + (g * 16 + k) * 20;
        const float* wrow_h = s_wh + (g * 16 + k) * 20;
        float acc_i = 0.0f, acc_h = 0.0f;
#pragma unroll
        for (int d4 = 0; d4 < 4; ++d4) {
            float4 wiv = *(const float4*)(wrow_i + d4 * 4);
            float4 whv = *(const float4*)(wrow_h + d4 * 4);
            acc_i += md[d4 * 4] * wiv.x + md[d4 * 4 + 1] * wiv.y
                   + md[d4 * 4 + 2] * wiv.z + md[d4 * 4 + 3] * wiv.w;
            acc_h += o[d4 * 4] * whv.x + o[d4 * 4 + 1] * whv.y
                   + o[d4 * 4 + 2] * whv.z + o[d4 * 4 + 3] * whv.w;
        }
        if (g == 0) { ir += acc_i; hr += acc_h; }
        else if (g == 1) { iz += acc_i; hz += acc_h; }
        else { in_ += acc_i; hh += acc_h; }
    }
    float rg = 1.0f / (1.0f + __expf(-(ir + hr)));
    float z  = 1.0f / (1.0f + __expf(-(iz + hz)));
    float nh = tanhf(in_ + rg * hh);
    float hnew = (1.0f - z) * nh + z * ok;

    if (last) out_final[n * 16 + k] = hnew;
    else      nxt[n * 16 + k] = hnew;
}

extern "C" void kernel_launch(void* const* d_in, const int* in_sizes, int n_in,
                              void* d_out, int out_size, void* d_ws, size_t ws_size,
                              hipStream_t stream) {
    const float* x         = (const float*)d_in[0];
    const int*   ei        = (const int*)d_in[1];
    const float* edge_attr = (const float*)d_in[2];
    const float* lin0_w    = (const float*)d_in[3];
    const float* lin0_b    = (const float*)d_in[4];
    const float* nn1_w     = (const float*)d_in[5];
    const float* nn1_b     = (const float*)d_in[6];
    const float* nn2_w     = (const float*)d_in[7];
    const float* nn2_b     = (const float*)d_in[8];
    const float* conv_root = (const float*)d_in[9];
    const float* conv_bias = (const float*)d_in[10];
    const float* gru_w_ih  = (const float*)d_in[11];
    const float* gru_w_hh  = (const float*)d_in[12];
    const float* gru_b_ih  = (const float*)d_in[13];
    const float* gru_b_hh  = (const float*)d_in[14];
    float* out = (float*)d_out;

    k_pre<<<NE / 256, 256, 0, stream>>>(ei, x, lin0_w, lin0_b);
    k_scan<<<1, 256, 0, stream>>>();
    k_scatter<<<NE / 256, 256, 0, stream>>>(ei, edge_attr, nn1_w, nn1_b);

    for (int r = 0; r < 6; ++r) {
        k_round<<<NN / 16, 256, 0, stream>>>(nn2_w, nn2_b, conv_root, conv_bias,
                                             gru_w_ih, gru_w_hh, gru_b_ih, gru_b_hh,
                                             out, r & 1, r == 5 ? 1 : 0);
    }
}